// Round 8
// baseline (269.739 us; speedup 1.0000x reference)
//
#include <hip/hip_runtime.h>

typedef __attribute__((ext_vector_type(8))) short short8;
typedef __attribute__((ext_vector_type(4))) float f32x4;
typedef __attribute__((ext_vector_type(16))) float f32x16;

#define T_TOK 16384
#define DM 512
#define NE 8
#define BM 64
#define ROWB 1040  // padded LDS row stride: 65*16B

__device__ __forceinline__ ushort f2bf(float v) {
  unsigned u = __float_as_uint(v);
  return (ushort)((u + 0x7FFFu + ((u >> 16) & 1u)) >> 16);
}

// ---------------- gating: logits + softmax, one wave per token ----------------
__global__ void gates_kernel(const float* __restrict__ x, const float* __restrict__ Wg,
                             const float* __restrict__ bg, float* __restrict__ gates) {
  int wid = (int)((blockIdx.x * blockDim.x + threadIdx.x) >> 6);
  int lane = threadIdx.x & 63;
  if (wid >= T_TOK) return;
  const float* xt = x + (size_t)wid * DM;
  float a[NE];
#pragma unroll
  for (int e = 0; e < NE; ++e) a[e] = 0.f;
  for (int d = lane; d < DM; d += 64) {
    float xv = xt[d];
    const float* wr = Wg + d * NE;
#pragma unroll
    for (int e = 0; e < NE; ++e) a[e] += xv * wr[e];
  }
#pragma unroll
  for (int e = 0; e < NE; ++e) {
#pragma unroll
    for (int off = 32; off > 0; off >>= 1) a[e] += __shfl_xor(a[e], off, 64);
  }
  float m = -1e30f;
#pragma unroll
  for (int e = 0; e < NE; ++e) { a[e] += bg[e]; m = fmaxf(m, a[e]); }
  float s = 0.f;
#pragma unroll
  for (int e = 0; e < NE; ++e) { a[e] = __expf(a[e] - m); s += a[e]; }
  float inv = 1.f / s;
  if (lane < NE) gates[(size_t)wid * NE + lane] = a[lane] * inv;
}

// -------- weight reorder: W[e][k][n] fp32 -> 32x32x16 A-fragment-major bf16 ----
// chunkid = (e*32 + kh)*16 + ft ; lane l holds
// W[e][kh*16 + (l>>5)*8 + j][ft*32 + (l&31)]  for j=0..7 (bf16).
__global__ void reorder_w_kernel(const float* __restrict__ W, ushort* __restrict__ WF) {
  int c = blockIdx.x * blockDim.x + threadIdx.x;  // 262144 threads
  int l = c & 63;
  int chunk = c >> 6;
  int ft = chunk & 15;
  int kh = (chunk >> 4) & 31;
  int e = chunk >> 9;
  int n = ft * 32 + (l & 31);
  int k0 = kh * 16 + (l >> 5) * 8;
  const float* src = W + ((size_t)e * DM + k0) * DM + n;
  short8 v;
#pragma unroll
  for (int j = 0; j < 8; ++j) v[j] = (short)f2bf(src[(size_t)j * DM]);
  *reinterpret_cast<short8*>(WF + (size_t)c * 8) = v;
}

// -------- x reorder: x fp32 -> 32x32x16 B-fragment-major bf16 --------
// thread c = ((m*16 + kt)*2 + ks)*2*64 + ni*64 + l ; lane l holds
// x[m*64 + ni*32 + (l&31)][kt*32 + ks*16 + (l>>5)*8 + j]  for j=0..7.
// EXACTLY 1,048,576 threads (= 16384*512/8). Grid must be 4096 x 256.
__global__ void reorder_x_kernel(const float* __restrict__ x, ushort* __restrict__ XF) {
  int c = blockIdx.x * blockDim.x + threadIdx.x;
  int l = c & 63;
  int ni = (c >> 6) & 1;
  int ks = (c >> 7) & 1;
  int kt = (c >> 8) & 15;
  int m = c >> 12;  // < 256
  int t = m * 64 + ni * 32 + (l & 31);
  int k0 = kt * 32 + ks * 16 + (l >> 5) * 8;
  const float* src = x + (size_t)t * DM + k0;
  short8 v;
#pragma unroll
  for (int j = 0; j < 8; ++j) v[j] = (short)f2bf(src[j]);
  *reinterpret_cast<short8*>(XF + (size_t)c * 8) = v;
}

// ---------------- fused MoE main kernel: producer/consumer wave split ----------
// 256 blocks x 512 threads. Waves 0-3 (A): GEMM1 for all experts, writing h to
// alternating LDS buffers. Waves 4-7 (B): GEMM2, consuming h one phase behind.
// Each wave owns 128 output cols; ONE shared acc[4][2] per wave (A resets per
// phase, B accumulates). 9 phases; on each SIMD an A-wave and a B-wave co-issue
// so MFMA never drains at phase boundaries.
__global__ __launch_bounds__(512, 2) void moe_main_kernel(
    const ushort* __restrict__ XF, const ushort* __restrict__ W1F,
    const float* __restrict__ b1, const ushort* __restrict__ W2F,
    const float* __restrict__ b2, const float* __restrict__ gates,
    float* __restrict__ out) {
  extern __shared__ char smem[];
  float* g_lds = (float*)(smem + 133120);  // [64][9] f32

  const int tid = threadIdx.x;
  const int lane = tid & 63;
  const int w = tid >> 6;
  const int hi = lane >> 5;
  const int l31 = lane & 31;
  const int m0 = blockIdx.x * BM;
  const bool isA = (w < 4);
  const int c0 = (w & 3) * 128;  // this wave's 128-col slice

  const unsigned abase = (unsigned)l31 * ROWB + (unsigned)hi * 16;             // B: h reads
  const unsigned wrbase = (unsigned)l31 * ROWB + (unsigned)(c0 * 2 + hi * 8);  // A: h writes

#define BARRIER()                                        \
  do {                                                   \
    asm volatile("s_waitcnt lgkmcnt(0)" ::: "memory");   \
    __builtin_amdgcn_s_barrier();                        \
  } while (0)

#define MF(d, a, b) d = __builtin_amdgcn_mfma_f32_32x32x16_bf16(a, b, d, 0, 0, 0)

  {  // gates -> LDS (padded stride 9)
    int t = tid >> 3, e = tid & 7;
    g_lds[t * 9 + e] = gates[(size_t)(m0 + t) * NE + e];
  }

  const short8* wgrp = reinterpret_cast<const short8*>(isA ? W1F : W2F) + (w & 3) * 256 + lane;
  const short8* xfp = reinterpret_cast<const short8*>(XF) + (size_t)blockIdx.x * 4096 + lane;

  f32x16 acc[4][2];
#pragma unroll
  for (int mi = 0; mi < 4; ++mi)
#pragma unroll
    for (int ni = 0; ni < 2; ++ni)
#pragma unroll
      for (int i = 0; i < 16; ++i) acc[mi][ni][i] = 0.f;

  short8 wA[2][8];

  BARRIER();  // gates staged

  for (int ph = 0; ph < 9; ++ph) {
    const bool on = isA ? (ph < 8) : (ph >= 1);
    if (on) {
      const int e = isA ? ph : (ph - 1);
      const short8* wp = wgrp + (size_t)e * 32768;
      char* hsrc = ((ph - 1) & 1) ? (smem + 66560) : smem;  // B's source buffer

      // kt0 weights
#pragma unroll
      for (int ks = 0; ks < 2; ++ks)
#pragma unroll
        for (int mi = 0; mi < 4; ++mi) wA[0][ks * 4 + mi] = wp[ks * 1024 + mi * 64];

#pragma unroll
      for (int kt = 0; kt < 16; ++kt) {
        if (kt < 15) {
#pragma unroll
          for (int ks = 0; ks < 2; ++ks)
#pragma unroll
            for (int mi = 0; mi < 4; ++mi)
              wA[(kt + 1) & 1][ks * 4 + mi] = wp[(kt + 1) * 2048 + ks * 1024 + mi * 64];
        }
        short8 a[4];
        if (isA) {
#pragma unroll
          for (int ks = 0; ks < 2; ++ks)
#pragma unroll
            for (int ni = 0; ni < 2; ++ni)
              a[ks * 2 + ni] = xfp[(kt * 4 + ks * 2 + ni) * 64];
        } else {
#pragma unroll
          for (int ks = 0; ks < 2; ++ks)
#pragma unroll
            for (int ni = 0; ni < 2; ++ni)
              a[ks * 2 + ni] = *reinterpret_cast<const short8*>(
                  hsrc + abase + ni * (32 * ROWB) + kt * 64 + ks * 32);
        }
        __builtin_amdgcn_s_setprio(1);
#pragma unroll
        for (int ks = 0; ks < 2; ++ks)
#pragma unroll
          for (int mi = 0; mi < 4; ++mi)
#pragma unroll
            for (int ni = 0; ni < 2; ++ni)
              MF(acc[mi][ni], wA[kt & 1][ks * 4 + mi], a[ks * 2 + ni]);
        __builtin_amdgcn_s_setprio(0);
      }

      if (isA) {
        // epilogue: h(ph)[t][f] = relu(acc + b1[f]) * g[t] -> hb[ph&1]; reset acc
        char* hdst = (ph & 1) ? (smem + 66560) : smem;
#pragma unroll
        for (int ni = 0; ni < 2; ++ni) {
          int t = ni * 32 + l31;
          float g = g_lds[t * 9 + ph];
#pragma unroll
          for (int mi = 0; mi < 4; ++mi) {
#pragma unroll
            for (int j = 0; j < 4; ++j) {
              float4 b1q = *reinterpret_cast<const float4*>(
                  b1 + ph * DM + c0 + mi * 32 + j * 8 + hi * 4);
              float v0 = fmaxf(acc[mi][ni][j * 4 + 0] + b1q.x, 0.f) * g;
              float v1 = fmaxf(acc[mi][ni][j * 4 + 1] + b1q.y, 0.f) * g;
              float v2 = fmaxf(acc[mi][ni][j * 4 + 2] + b1q.z, 0.f) * g;
              float v3 = fmaxf(acc[mi][ni][j * 4 + 3] + b1q.w, 0.f) * g;
              unsigned lo = (unsigned)f2bf(v0) | ((unsigned)f2bf(v1) << 16);
              unsigned hb_ = (unsigned)f2bf(v2) | ((unsigned)f2bf(v3) << 16);
              *reinterpret_cast<uint2*>(hdst + wrbase + ni * (32 * ROWB) + mi * 64 + j * 16) =
                  make_uint2(lo, hb_);
            }
          }
        }
#pragma unroll
        for (int mi = 0; mi < 4; ++mi)
#pragma unroll
          for (int ni = 0; ni < 2; ++ni)
#pragma unroll
            for (int i = 0; i < 16; ++i) acc[mi][ni][i] = 0.f;
      }
    }
    BARRIER();
  }

  if (!isA) {
    // fold Sum_e gate[t][e] * b2[e][d]
#pragma unroll
    for (int e = 0; e < NE; ++e) {
      float ge0 = g_lds[l31 * 9 + e];
      float ge1 = g_lds[(32 + l31) * 9 + e];
#pragma unroll
      for (int mi = 0; mi < 4; ++mi)
#pragma unroll
        for (int j = 0; j < 4; ++j) {
          float4 b2q = *reinterpret_cast<const float4*>(
              b2 + e * DM + c0 + mi * 32 + j * 8 + hi * 4);
          acc[mi][0][j * 4 + 0] += ge0 * b2q.x;
          acc[mi][0][j * 4 + 1] += ge0 * b2q.y;
          acc[mi][0][j * 4 + 2] += ge0 * b2q.z;
          acc[mi][0][j * 4 + 3] += ge0 * b2q.w;
          acc[mi][1][j * 4 + 0] += ge1 * b2q.x;
          acc[mi][1][j * 4 + 1] += ge1 * b2q.y;
          acc[mi][1][j * 4 + 2] += ge1 * b2q.z;
          acc[mi][1][j * 4 + 3] += ge1 * b2q.w;
        }
    }
    // write out
#pragma unroll
    for (int ni = 0; ni < 2; ++ni) {
      int t = m0 + ni * 32 + l31;
#pragma unroll
      for (int mi = 0; mi < 4; ++mi)
#pragma unroll
        for (int j = 0; j < 4; ++j) {
          f32x4 v;
          v[0] = acc[mi][ni][j * 4 + 0];
          v[1] = acc[mi][ni][j * 4 + 1];
          v[2] = acc[mi][ni][j * 4 + 2];
          v[3] = acc[mi][ni][j * 4 + 3];
          *reinterpret_cast<f32x4*>(out + (size_t)t * DM + c0 + mi * 32 + j * 8 + hi * 4) = v;
        }
    }
  }
#undef MF
#undef BARRIER
}

extern "C" void kernel_launch(void* const* d_in, const int* in_sizes, int n_in,
                              void* d_out, int out_size, void* d_ws, size_t ws_size,
                              hipStream_t stream) {
  const float* x  = (const float*)d_in[0];
  const float* W1 = (const float*)d_in[1];
  const float* b1 = (const float*)d_in[2];
  const float* W2 = (const float*)d_in[3];
  const float* b2 = (const float*)d_in[4];
  const float* Wg = (const float*)d_in[5];
  const float* bg = (const float*)d_in[6];
  float* out = (float*)d_out;

  float* gates = (float*)d_ws;                               // 512 KiB
  ushort* W1F = (ushort*)((char*)d_ws + 524288);             // 4 MiB
  ushort* W2F = (ushort*)((char*)d_ws + 4718592);            // 4 MiB
  ushort* XF  = (ushort*)((char*)d_ws + 8912896);            // 16 MiB

  hipFuncSetAttribute((const void*)moe_main_kernel,
                      hipFuncAttributeMaxDynamicSharedMemorySize, 135424);

  gates_kernel<<<T_TOK / 4, 256, 0, stream>>>(x, Wg, bg, gates);
  reorder_w_kernel<<<1024, 256, 0, stream>>>(W1, W1F);
  reorder_w_kernel<<<1024, 256, 0, stream>>>(W2, W2F);
  reorder_x_kernel<<<4096, 256, 0, stream>>>(x, XF);  // exactly 2^20 threads
  moe_main_kernel<<<T_TOK / BM, 512, 135424, stream>>>(XF, W1F, b1, W2F, b2, gates, out);
}

// Round 9
// 244.054 us; speedup vs baseline: 1.1052x; 1.1052x over previous
//
#include <hip/hip_runtime.h>

typedef __attribute__((ext_vector_type(8))) short short8;
typedef __attribute__((ext_vector_type(4))) float f32x4;
typedef __attribute__((ext_vector_type(16))) float f32x16;

#define T_TOK 16384
#define DM 512
#define NE 8
#define BM 64
#define ROWB 1040  // padded LDS row stride: 65*16B

__device__ __forceinline__ ushort f2bf(float v) {
  unsigned u = __float_as_uint(v);
  return (ushort)((u + 0x7FFFu + ((u >> 16) & 1u)) >> 16);
}

// ---------------- gating: logits + softmax, one wave per token ----------------
__global__ void gates_kernel(const float* __restrict__ x, const float* __restrict__ Wg,
                             const float* __restrict__ bg, float* __restrict__ gates) {
  int wid = (int)((blockIdx.x * blockDim.x + threadIdx.x) >> 6);
  int lane = threadIdx.x & 63;
  if (wid >= T_TOK) return;
  const float* xt = x + (size_t)wid * DM;
  float a[NE];
#pragma unroll
  for (int e = 0; e < NE; ++e) a[e] = 0.f;
  for (int d = lane; d < DM; d += 64) {
    float xv = xt[d];
    const float* wr = Wg + d * NE;
#pragma unroll
    for (int e = 0; e < NE; ++e) a[e] += xv * wr[e];
  }
#pragma unroll
  for (int e = 0; e < NE; ++e) {
#pragma unroll
    for (int off = 32; off > 0; off >>= 1) a[e] += __shfl_xor(a[e], off, 64);
  }
  float m = -1e30f;
#pragma unroll
  for (int e = 0; e < NE; ++e) { a[e] += bg[e]; m = fmaxf(m, a[e]); }
  float s = 0.f;
#pragma unroll
  for (int e = 0; e < NE; ++e) { a[e] = __expf(a[e] - m); s += a[e]; }
  float inv = 1.f / s;
  if (lane < NE) gates[(size_t)wid * NE + lane] = a[lane] * inv;
}

// -------- weight reorder: W[e][k][n] fp32 -> 32x32x16 A-fragment-major bf16 ----
// chunkid = (e*32 + kh)*16 + ft ; lane l holds
// W[e][kh*16 + (l>>5)*8 + j][ft*32 + (l&31)]  for j=0..7 (bf16).
__global__ void reorder_w_kernel(const float* __restrict__ W, ushort* __restrict__ WF) {
  int c = blockIdx.x * blockDim.x + threadIdx.x;  // 262144 threads
  int l = c & 63;
  int chunk = c >> 6;
  int ft = chunk & 15;
  int kh = (chunk >> 4) & 31;
  int e = chunk >> 9;
  int n = ft * 32 + (l & 31);
  int k0 = kh * 16 + (l >> 5) * 8;
  const float* src = W + ((size_t)e * DM + k0) * DM + n;
  short8 v;
#pragma unroll
  for (int j = 0; j < 8; ++j) v[j] = (short)f2bf(src[(size_t)j * DM]);
  *reinterpret_cast<short8*>(WF + (size_t)c * 8) = v;
}

// -------- x reorder: x fp32 -> 32x32x16 B-fragment-major bf16 --------
// thread c ; lane l holds x[m*64 + ni*32 + (l&31)][kt*32 + ks*16 + (l>>5)*8 + j].
// EXACTLY 1,048,576 threads (= 16384*512/8). Grid must be 4096 x 256.
__global__ void reorder_x_kernel(const float* __restrict__ x, ushort* __restrict__ XF) {
  int c = blockIdx.x * blockDim.x + threadIdx.x;
  int l = c & 63;
  int ni = (c >> 6) & 1;
  int ks = (c >> 7) & 1;
  int kt = (c >> 8) & 15;
  int m = c >> 12;  // < 256
  int t = m * 64 + ni * 32 + (l & 31);
  int k0 = kt * 32 + ks * 16 + (l >> 5) * 8;
  const float* src = x + (size_t)t * DM + k0;
  short8 v;
#pragma unroll
  for (int j = 0; j < 8; ++j) v[j] = (short)f2bf(src[j]);
  *reinterpret_cast<short8*>(XF + (size_t)c * 8) = v;
}

// ---------------- fused MoE main kernel: producer/consumer wave split ----------
// 256 blocks x 512 threads. Waves 0-3 (A): GEMM1 all experts -> h (alternating
// LDS buffers). Waves 4-7 (B): GEMM2 one phase behind, acc across experts.
// Half-kt software pipeline: wA[2][4] + a[2][2] double buffers (~210 regs total,
// no spill). A/B stagger on each SIMD covers epilogue VALU under MFMAs.
__global__ __launch_bounds__(512, 2) void moe_main_kernel(
    const ushort* __restrict__ XF, const ushort* __restrict__ W1F,
    const float* __restrict__ b1, const ushort* __restrict__ W2F,
    const float* __restrict__ b2, const float* __restrict__ gates,
    float* __restrict__ out) {
  extern __shared__ char smem[];
  float* g_lds = (float*)(smem + 133120);  // [64][9] f32

  const int tid = threadIdx.x;
  const int lane = tid & 63;
  const int w = tid >> 6;
  const int hi = lane >> 5;
  const int l31 = lane & 31;
  const int m0 = blockIdx.x * BM;
  const bool isA = (w < 4);
  const int c0 = (w & 3) * 128;  // this wave's 128-col slice

  const unsigned abase = (unsigned)l31 * ROWB + (unsigned)hi * 16;             // B: h reads
  const unsigned wrbase = (unsigned)l31 * ROWB + (unsigned)(c0 * 2 + hi * 8);  // A: h writes

#define BARRIER()                                        \
  do {                                                   \
    asm volatile("s_waitcnt lgkmcnt(0)" ::: "memory");   \
    __builtin_amdgcn_s_barrier();                        \
  } while (0)

#define MF(d, a, b) d = __builtin_amdgcn_mfma_f32_32x32x16_bf16(a, b, d, 0, 0, 0)

  {  // gates -> LDS (padded stride 9)
    int t = tid >> 3, e = tid & 7;
    g_lds[t * 9 + e] = gates[(size_t)(m0 + t) * NE + e];
  }

  const short8* wgrp = reinterpret_cast<const short8*>(isA ? W1F : W2F) + (w & 3) * 256 + lane;
  const short8* xfp = reinterpret_cast<const short8*>(XF) + (size_t)blockIdx.x * 4096 + lane;

  f32x16 acc[4][2];
#pragma unroll
  for (int mi = 0; mi < 4; ++mi)
#pragma unroll
    for (int ni = 0; ni < 2; ++ni)
#pragma unroll
      for (int i = 0; i < 16; ++i) acc[mi][ni][i] = 0.f;

  short8 wA[2][4];  // weight frags, half-kt double buffer
  short8 af[2][2];  // act frags, half-kt double buffer

  BARRIER();  // gates staged

  for (int ph = 0; ph < 9; ++ph) {
    const bool on = isA ? (ph < 8) : (ph >= 1);
    if (on) {
      const int e = isA ? ph : (ph - 1);
      const short8* wp = wgrp + (size_t)e * 32768;
      char* hsrc = ((ph - 1) & 1) ? (smem + 66560) : smem;  // B's source buffer

      // h=0 prologue: 4 weight frags + 2 act frags
#pragma unroll
      for (int mi = 0; mi < 4; ++mi) wA[0][mi] = wp[mi * 64];
      if (isA) {
#pragma unroll
        for (int ni = 0; ni < 2; ++ni) af[0][ni] = xfp[ni * 64];
      } else {
#pragma unroll
        for (int ni = 0; ni < 2; ++ni)
          af[0][ni] = *reinterpret_cast<const short8*>(hsrc + abase + ni * (32 * ROWB));
      }

      // 32 half-kt steps, 1-ahead prefetch, 8 MFMA each
#pragma unroll
      for (int h = 0; h < 32; ++h) {
        if (h < 31) {
#pragma unroll
          for (int mi = 0; mi < 4; ++mi)
            wA[(h + 1) & 1][mi] = wp[(h + 1) * 1024 + mi * 64];
          if (isA) {
#pragma unroll
            for (int ni = 0; ni < 2; ++ni)
              af[(h + 1) & 1][ni] = xfp[((h + 1) * 2 + ni) * 64];
          } else {
#pragma unroll
            for (int ni = 0; ni < 2; ++ni)
              af[(h + 1) & 1][ni] = *reinterpret_cast<const short8*>(
                  hsrc + abase + ni * (32 * ROWB) + (h + 1) * 32);
          }
        }
        __builtin_amdgcn_s_setprio(1);
#pragma unroll
        for (int mi = 0; mi < 4; ++mi)
#pragma unroll
          for (int ni = 0; ni < 2; ++ni)
            MF(acc[mi][ni], wA[h & 1][mi], af[h & 1][ni]);
        __builtin_amdgcn_s_setprio(0);
      }

      if (isA) {
        // epilogue: h(ph)[t][f] = relu(acc + b1[f]) * g[t] -> hb[ph&1]; reset acc
        char* hdst = (ph & 1) ? (smem + 66560) : smem;
#pragma unroll
        for (int ni = 0; ni < 2; ++ni) {
          int t = ni * 32 + l31;
          float g = g_lds[t * 9 + ph];
#pragma unroll
          for (int mi = 0; mi < 4; ++mi) {
#pragma unroll
            for (int j = 0; j < 4; ++j) {
              float4 b1q = *reinterpret_cast<const float4*>(
                  b1 + ph * DM + c0 + mi * 32 + j * 8 + hi * 4);
              float v0 = fmaxf(acc[mi][ni][j * 4 + 0] + b1q.x, 0.f) * g;
              float v1 = fmaxf(acc[mi][ni][j * 4 + 1] + b1q.y, 0.f) * g;
              float v2 = fmaxf(acc[mi][ni][j * 4 + 2] + b1q.z, 0.f) * g;
              float v3 = fmaxf(acc[mi][ni][j * 4 + 3] + b1q.w, 0.f) * g;
              unsigned lo = (unsigned)f2bf(v0) | ((unsigned)f2bf(v1) << 16);
              unsigned hb_ = (unsigned)f2bf(v2) | ((unsigned)f2bf(v3) << 16);
              *reinterpret_cast<uint2*>(hdst + wrbase + ni * (32 * ROWB) + mi * 64 + j * 16) =
                  make_uint2(lo, hb_);
            }
          }
        }
#pragma unroll
        for (int mi = 0; mi < 4; ++mi)
#pragma unroll
          for (int ni = 0; ni < 2; ++ni)
#pragma unroll
            for (int i = 0; i < 16; ++i) acc[mi][ni][i] = 0.f;
      }
    }
    BARRIER();
  }

  if (!isA) {
    // fold Sum_e gate[t][e] * b2[e][d]
#pragma unroll
    for (int e = 0; e < NE; ++e) {
      float ge0 = g_lds[l31 * 9 + e];
      float ge1 = g_lds[(32 + l31) * 9 + e];
#pragma unroll
      for (int mi = 0; mi < 4; ++mi)
#pragma unroll
        for (int j = 0; j < 4; ++j) {
          float4 b2q = *reinterpret_cast<const float4*>(
              b2 + e * DM + c0 + mi * 32 + j * 8 + hi * 4);
          acc[mi][0][j * 4 + 0] += ge0 * b2q.x;
          acc[mi][0][j * 4 + 1] += ge0 * b2q.y;
          acc[mi][0][j * 4 + 2] += ge0 * b2q.z;
          acc[mi][0][j * 4 + 3] += ge0 * b2q.w;
          acc[mi][1][j * 4 + 0] += ge1 * b2q.x;
          acc[mi][1][j * 4 + 1] += ge1 * b2q.y;
          acc[mi][1][j * 4 + 2] += ge1 * b2q.z;
          acc[mi][1][j * 4 + 3] += ge1 * b2q.w;
        }
    }
    // write out
#pragma unroll
    for (int ni = 0; ni < 2; ++ni) {
      int t = m0 + ni * 32 + l31;
#pragma unroll
      for (int mi = 0; mi < 4; ++mi)
#pragma unroll
        for (int j = 0; j < 4; ++j) {
          f32x4 v;
          v[0] = acc[mi][ni][j * 4 + 0];
          v[1] = acc[mi][ni][j * 4 + 1];
          v[2] = acc[mi][ni][j * 4 + 2];
          v[3] = acc[mi][ni][j * 4 + 3];
          *reinterpret_cast<f32x4*>(out + (size_t)t * DM + c0 + mi * 32 + j * 8 + hi * 4) = v;
        }
    }
  }
#undef MF
#undef BARRIER
}

extern "C" void kernel_launch(void* const* d_in, const int* in_sizes, int n_in,
                              void* d_out, int out_size, void* d_ws, size_t ws_size,
                              hipStream_t stream) {
  const float* x  = (const float*)d_in[0];
  const float* W1 = (const float*)d_in[1];
  const float* b1 = (const float*)d_in[2];
  const float* W2 = (const float*)d_in[3];
  const float* b2 = (const float*)d_in[4];
  const float* Wg = (const float*)d_in[5];
  const float* bg = (const float*)d_in[6];
  float* out = (float*)d_out;

  float* gates = (float*)d_ws;                               // 512 KiB
  ushort* W1F = (ushort*)((char*)d_ws + 524288);             // 4 MiB
  ushort* W2F = (ushort*)((char*)d_ws + 4718592);            // 4 MiB
  ushort* XF  = (ushort*)((char*)d_ws + 8912896);            // 16 MiB

  hipFuncSetAttribute((const void*)moe_main_kernel,
                      hipFuncAttributeMaxDynamicSharedMemorySize, 135424);

  gates_kernel<<<T_TOK / 4, 256, 0, stream>>>(x, Wg, bg, gates);
  reorder_w_kernel<<<1024, 256, 0, stream>>>(W1, W1F);
  reorder_w_kernel<<<1024, 256, 0, stream>>>(W2, W2F);
  reorder_x_kernel<<<4096, 256, 0, stream>>>(x, XF);  // exactly 2^20 threads
  moe_main_kernel<<<T_TOK / BM, 512, 135424, stream>>>(XF, W1F, b1, W2F, b2, gates, out);
}

// Round 10
// 163.418 us; speedup vs baseline: 1.6506x; 1.4934x over previous
//
#include <hip/hip_runtime.h>

typedef __attribute__((ext_vector_type(8))) short short8;
typedef __attribute__((ext_vector_type(4))) float f32x4;
typedef __attribute__((ext_vector_type(16))) float f32x16;

#define T_TOK 16384
#define DM 512
#define NE 8
#define BM 64
#define ROWB 1040  // padded LDS row stride: 65*16B -> bank-slot rotates by 1/row

__device__ __forceinline__ ushort f2bf(float v) {
  unsigned u = __float_as_uint(v);
  return (ushort)((u + 0x7FFFu + ((u >> 16) & 1u)) >> 16);
}

// pack two f32 -> one u32 of 2 bf16 (RNE) in a single VALU op
__device__ __forceinline__ unsigned pk2bf(float a, float b) {
  unsigned r;
  asm("v_cvt_pk_bf16_f32 %0, %1, %2" : "=v"(r) : "v"(a), "v"(b));
  return r;
}

// ---------------- gating: logits + softmax, one wave per token ----------------
__global__ void gates_kernel(const float* __restrict__ x, const float* __restrict__ Wg,
                             const float* __restrict__ bg, float* __restrict__ gates) {
  int wid = (int)((blockIdx.x * blockDim.x + threadIdx.x) >> 6);
  int lane = threadIdx.x & 63;
  if (wid >= T_TOK) return;
  const float* xt = x + (size_t)wid * DM;
  float a[NE];
#pragma unroll
  for (int e = 0; e < NE; ++e) a[e] = 0.f;
  for (int d = lane; d < DM; d += 64) {
    float xv = xt[d];
    const float* wr = Wg + d * NE;
#pragma unroll
    for (int e = 0; e < NE; ++e) a[e] += xv * wr[e];
  }
#pragma unroll
  for (int e = 0; e < NE; ++e) {
#pragma unroll
    for (int off = 32; off > 0; off >>= 1) a[e] += __shfl_xor(a[e], off, 64);
  }
  float m = -1e30f;
#pragma unroll
  for (int e = 0; e < NE; ++e) { a[e] += bg[e]; m = fmaxf(m, a[e]); }
  float s = 0.f;
#pragma unroll
  for (int e = 0; e < NE; ++e) { a[e] = __expf(a[e] - m); s += a[e]; }
  float inv = 1.f / s;
  if (lane < NE) gates[(size_t)wid * NE + lane] = a[lane] * inv;
}

// -------- weight reorder: W[e][k][n] fp32 -> 32x32x16 A-fragment-major bf16 ----
// chunkid = (e*32 + kh)*16 + ft ; lane l holds
// W[e][kh*16 + (l>>5)*8 + j][ft*32 + (l&31)]  for j=0..7 (bf16).
__global__ void reorder_w_kernel(const float* __restrict__ W, ushort* __restrict__ WF) {
  int c = blockIdx.x * blockDim.x + threadIdx.x;  // 262144 threads
  int l = c & 63;
  int chunk = c >> 6;
  int ft = chunk & 15;
  int kh = (chunk >> 4) & 31;
  int e = chunk >> 9;
  int n = ft * 32 + (l & 31);
  int k0 = kh * 16 + (l >> 5) * 8;
  const float* src = W + ((size_t)e * DM + k0) * DM + n;
  short8 v;
#pragma unroll
  for (int j = 0; j < 8; ++j) v[j] = (short)f2bf(src[(size_t)j * DM]);
  *reinterpret_cast<short8*>(WF + (size_t)c * 8) = v;
}

// ---------------- fused MoE main kernel ----------------
// 256 blocks x 512 threads (8 waves). Wave w owns output cols [w*64, w*64+64).
// 32x32x16 MFMA, swapped operands: D[f][t] = mfma(A=W-frag, B=act-frag).
// Raw s_barrier + lgkmcnt-only drain: weight prefetches stay in flight
// across barriers. Padded LDS rows (1040B) -> conflict-free, additive addressing.
__global__ __launch_bounds__(512, 2) void moe_main_kernel(
    const float* __restrict__ x, const ushort* __restrict__ W1F,
    const float* __restrict__ b1, const ushort* __restrict__ W2F,
    const float* __restrict__ b2, const float* __restrict__ gates,
    float* __restrict__ out) {
  extern __shared__ char smem[];
  char* x_lds = smem;                        // 64 rows * 1040 B = 66560
  char* h_lds = smem + 66560;                // 66560
  float* g_lds = (float*)(smem + 133120);    // [64][9] f32

  const int tid = threadIdx.x;
  const int lane = tid & 63;
  const int w = tid >> 6;        // wave 0..7
  const int hi = lane >> 5;      // k-half
  const int l31 = lane & 31;
  const int m0 = blockIdx.x * BM;

  const unsigned abase = (unsigned)l31 * ROWB + (unsigned)hi * 16;
  const unsigned wbase = (unsigned)l31 * ROWB + (unsigned)(w * 128 + hi * 8);

#define BARRIER()                                        \
  do {                                                   \
    asm volatile("s_waitcnt lgkmcnt(0)" ::: "memory");   \
    __builtin_amdgcn_s_barrier();                        \
  } while (0)

#define LDACT(lds, kt, ks, ni) \
  (*reinterpret_cast<const short8*>((lds) + abase + (ni) * (32 * ROWB) + ((kt) * 64 + (ks) * 32)))

#define MF(d, a, b) d = __builtin_amdgcn_mfma_f32_32x32x16_bf16(a, b, d, 0, 0, 0)

  {  // gates -> LDS (padded stride 9)
    int t = tid >> 3, e = tid & 7;
    g_lds[t * 9 + e] = gates[(size_t)(m0 + t) * NE + e];
  }

  // stage x tile: fp32 -> bf16 via cvt_pk, padded rows
  for (int i = tid; i < BM * DM / 4; i += 512) {
    int t = i >> 7;
    int kd = (i & 127) * 4;
    float4 v = *reinterpret_cast<const float4*>(x + ((size_t)(m0 + t) << 9) + kd);
    unsigned lo = pk2bf(v.x, v.y);
    unsigned hb = pk2bf(v.z, v.w);
    *reinterpret_cast<uint2*>(x_lds + (unsigned)(t * ROWB + kd * 2)) = make_uint2(lo, hb);
  }
  BARRIER();

  const short8* wp1 = reinterpret_cast<const short8*>(W1F) + w * 128 + lane;
  const short8* wp2 = reinterpret_cast<const short8*>(W2F) + w * 128 + lane;

  f32x16 acc[2][2];
#pragma unroll
  for (int mi = 0; mi < 2; ++mi)
#pragma unroll
    for (int ni = 0; ni < 2; ++ni)
#pragma unroll
      for (int i = 0; i < 16; ++i) acc[mi][ni][i] = 0.f;

  short8 wb[3][4], ab[2][4];

  // e=0 GEMM1 prologue: kt0 -> wb[2], kt1 -> wb[0]; act kt0 -> ab[0]
#pragma unroll
  for (int ks = 0; ks < 2; ++ks)
#pragma unroll
    for (int mi = 0; mi < 2; ++mi) {
      wb[2][ks * 2 + mi] = wp1[ks * 1024 + mi * 64];
      wb[0][ks * 2 + mi] = wp1[2048 + ks * 1024 + mi * 64];
    }
#pragma unroll
  for (int ks = 0; ks < 2; ++ks)
#pragma unroll
    for (int ni = 0; ni < 2; ++ni) ab[0][ks * 2 + ni] = LDACT(x_lds, 0, ks, ni);

  for (int e = 0; e < NE; ++e) {
    const short8* we1 = wp1 + (size_t)e * 32768;
    const short8* we2 = wp2 + (size_t)e * 32768;

    // ---------- GEMM1: h^T[f][t] = sum_k W1[k][f] * x[t][k] ----------
    f32x16 hacc[2][2];
#pragma unroll
    for (int mi = 0; mi < 2; ++mi)
#pragma unroll
      for (int ni = 0; ni < 2; ++ni)
#pragma unroll
        for (int i = 0; i < 16; ++i) hacc[mi][ni][i] = 0.f;

#pragma unroll
    for (int kt = 0; kt < 16; ++kt) {
      if (kt < 14) {
#pragma unroll
        for (int ks = 0; ks < 2; ++ks)
#pragma unroll
          for (int mi = 0; mi < 2; ++mi)
            wb[(kt + 1) % 3][ks * 2 + mi] = we1[(kt + 2) * 2048 + ks * 1024 + mi * 64];
      }
      if (kt < 15) {
#pragma unroll
        for (int ks = 0; ks < 2; ++ks)
#pragma unroll
          for (int ni = 0; ni < 2; ++ni)
            ab[(kt + 1) % 2][ks * 2 + ni] = LDACT(x_lds, kt + 1, ks, ni);
      }
      __builtin_amdgcn_s_setprio(1);
#pragma unroll
      for (int ks = 0; ks < 2; ++ks)
#pragma unroll
        for (int mi = 0; mi < 2; ++mi)
#pragma unroll
          for (int ni = 0; ni < 2; ++ni)
            MF(hacc[mi][ni], wb[(kt + 2) % 3][ks * 2 + mi], ab[kt % 2][ks * 2 + ni]);
      __builtin_amdgcn_s_setprio(0);
    }

    // GEMM2 weight prologue (stays in flight across barrier): kt0 -> wb[1], kt1 -> wb[2]
#pragma unroll
    for (int ks = 0; ks < 2; ++ks)
#pragma unroll
      for (int mi = 0; mi < 2; ++mi) {
        wb[1][ks * 2 + mi] = we2[ks * 1024 + mi * 64];
        wb[2][ks * 2 + mi] = we2[2048 + ks * 1024 + mi * 64];
      }

    // epilogue: h[t][f] = relu(hacc + b1[f]) * g[t] -> h_lds (cvt_pk + b64 writes)
#pragma unroll
    for (int ni = 0; ni < 2; ++ni) {
      int t = ni * 32 + l31;
      float g = g_lds[t * 9 + e];
#pragma unroll
      for (int mi = 0; mi < 2; ++mi) {
#pragma unroll
        for (int j = 0; j < 4; ++j) {
          float4 b1q = *reinterpret_cast<const float4*>(
              b1 + e * DM + w * 64 + mi * 32 + j * 8 + hi * 4);
          float v0 = fmaxf(hacc[mi][ni][j * 4 + 0] + b1q.x, 0.f) * g;
          float v1 = fmaxf(hacc[mi][ni][j * 4 + 1] + b1q.y, 0.f) * g;
          float v2 = fmaxf(hacc[mi][ni][j * 4 + 2] + b1q.z, 0.f) * g;
          float v3 = fmaxf(hacc[mi][ni][j * 4 + 3] + b1q.w, 0.f) * g;
          unsigned lo = pk2bf(v0, v1);
          unsigned hb = pk2bf(v2, v3);
          *reinterpret_cast<uint2*>(h_lds + wbase + ni * (32 * ROWB) + mi * 64 + j * 16) =
              make_uint2(lo, hb);
        }
      }
    }
    BARRIER();

    // ---------- GEMM2: acc[d][t] += sum_f W2[f][d] * h[t][f] ----------
#pragma unroll
    for (int ks = 0; ks < 2; ++ks)
#pragma unroll
      for (int ni = 0; ni < 2; ++ni) ab[0][ks * 2 + ni] = LDACT(h_lds, 0, ks, ni);

#pragma unroll
    for (int kt = 0; kt < 16; ++kt) {
      if (kt < 14) {
#pragma unroll
        for (int ks = 0; ks < 2; ++ks)
#pragma unroll
          for (int mi = 0; mi < 2; ++mi)
            wb[kt % 3][ks * 2 + mi] = we2[(kt + 2) * 2048 + ks * 1024 + mi * 64];
      }
      if (kt < 15) {
#pragma unroll
        for (int ks = 0; ks < 2; ++ks)
#pragma unroll
          for (int ni = 0; ni < 2; ++ni)
            ab[(kt + 1) % 2][ks * 2 + ni] = LDACT(h_lds, kt + 1, ks, ni);
      }
      __builtin_amdgcn_s_setprio(1);
#pragma unroll
      for (int ks = 0; ks < 2; ++ks)
#pragma unroll
        for (int mi = 0; mi < 2; ++mi)
#pragma unroll
          for (int ni = 0; ni < 2; ++ni)
            MF(acc[mi][ni], wb[(kt + 1) % 3][ks * 2 + mi], ab[kt % 2][ks * 2 + ni]);
      __builtin_amdgcn_s_setprio(0);
    }

    // next-expert GEMM1 prologue (stays in flight across barrier)
    if (e < NE - 1) {
      const short8* wn1 = we1 + 32768;
#pragma unroll
      for (int ks = 0; ks < 2; ++ks)
#pragma unroll
        for (int mi = 0; mi < 2; ++mi) {
          wb[2][ks * 2 + mi] = wn1[ks * 1024 + mi * 64];
          wb[0][ks * 2 + mi] = wn1[2048 + ks * 1024 + mi * 64];
        }
#pragma unroll
      for (int ks = 0; ks < 2; ++ks)
#pragma unroll
        for (int ni = 0; ni < 2; ++ni) ab[0][ks * 2 + ni] = LDACT(x_lds, 0, ks, ni);
    }
    BARRIER();
  }

  // fold Sum_e gate[t][e] * b2[e][d] ONCE (outside the barrier-locked loop)
#pragma unroll
  for (int e = 0; e < NE; ++e) {
    float ge0 = g_lds[l31 * 9 + e];
    float ge1 = g_lds[(32 + l31) * 9 + e];
#pragma unroll
    for (int mi = 0; mi < 2; ++mi)
#pragma unroll
      for (int j = 0; j < 4; ++j) {
        float4 b2q = *reinterpret_cast<const float4*>(
            b2 + e * DM + w * 64 + mi * 32 + j * 8 + hi * 4);
        acc[mi][0][j * 4 + 0] += ge0 * b2q.x;
        acc[mi][0][j * 4 + 1] += ge0 * b2q.y;
        acc[mi][0][j * 4 + 2] += ge0 * b2q.z;
        acc[mi][0][j * 4 + 3] += ge0 * b2q.w;
        acc[mi][1][j * 4 + 0] += ge1 * b2q.x;
        acc[mi][1][j * 4 + 1] += ge1 * b2q.y;
        acc[mi][1][j * 4 + 2] += ge1 * b2q.z;
        acc[mi][1][j * 4 + 3] += ge1 * b2q.w;
      }
  }

  // write out: per (mi,ni,j) a float4 of consecutive d
#pragma unroll
  for (int ni = 0; ni < 2; ++ni) {
    int t = m0 + ni * 32 + l31;
#pragma unroll
    for (int mi = 0; mi < 2; ++mi)
#pragma unroll
      for (int j = 0; j < 4; ++j) {
        f32x4 v;
        v[0] = acc[mi][ni][j * 4 + 0];
        v[1] = acc[mi][ni][j * 4 + 1];
        v[2] = acc[mi][ni][j * 4 + 2];
        v[3] = acc[mi][ni][j * 4 + 3];
        *reinterpret_cast<f32x4*>(out + (size_t)t * DM + w * 64 + mi * 32 + j * 8 + hi * 4) = v;
      }
  }
#undef LDACT
#undef MF
#undef BARRIER
}

extern "C" void kernel_launch(void* const* d_in, const int* in_sizes, int n_in,
                              void* d_out, int out_size, void* d_ws, size_t ws_size,
                              hipStream_t stream) {
  const float* x  = (const float*)d_in[0];
  const float* W1 = (const float*)d_in[1];
  const float* b1 = (const float*)d_in[2];
  const float* W2 = (const float*)d_in[3];
  const float* b2 = (const float*)d_in[4];
  const float* Wg = (const float*)d_in[5];
  const float* bg = (const float*)d_in[6];
  float* out = (float*)d_out;

  float* gates = (float*)d_ws;                              // 512 KiB
  ushort* W1F = (ushort*)((char*)d_ws + 524288);            // 4 MiB
  ushort* W2F = (ushort*)((char*)d_ws + 524288 + 4194304);  // 4 MiB

  hipFuncSetAttribute((const void*)moe_main_kernel,
                      hipFuncAttributeMaxDynamicSharedMemorySize, 135424);

  gates_kernel<<<T_TOK / 4, 256, 0, stream>>>(x, Wg, bg, gates);
  reorder_w_kernel<<<1024, 256, 0, stream>>>(W1, W1F);
  reorder_w_kernel<<<1024, 256, 0, stream>>>(W2, W2F);
  moe_main_kernel<<<T_TOK / BM, 512, 135424, stream>>>(x, W1F, b1, W2F, b2, gates, out);
}